// Round 5
// baseline (701.233 us; speedup 1.0000x reference)
//
#include <hip/hip_runtime.h>

#define NB 4
#define NN 200000
#define HH 512
#define WW 512
#define CC 64
#define PP 150000
#define RP 100000
#define HWSZ (HH * WW)
#define NPTS (NB * NN)
#define XSHIFT 4                      // 16 floats = one 64B line along x
#define BINS_PER_B (HH * (WW >> XSHIFT))   // 512*32 = 16384
#define NBINS (NB * BINS_PER_B)            // 65536
// wbuf: Wcat f32[160*32] | Wtail f32[6*32] | bcat f32[32] | pad -> 5376 floats
//       then W2h uint[40*64] (f16 pairs)   -> total 8192 words
#define WCAT_PAD 5376
#define WBUF_WORDS 8192

typedef _Float16 half2_t __attribute__((ext_vector_type(2)));

__device__ __forceinline__ half2_t u2h(unsigned u) { half2_t h; __builtin_memcpy(&h, &u, 4); return h; }
__device__ __forceinline__ unsigned h2u(half2_t h) { unsigned u; __builtin_memcpy(&u, &h, 4); return u; }
__device__ __forceinline__ unsigned packh(float a, float b) {
    half2_t h; h.x = (_Float16)a; h.y = (_Float16)b; return h2u(h);
}

#if __has_builtin(__builtin_amdgcn_fdot2)
#define HAS_FDOT2 1
#else
#define HAS_FDOT2 0
#endif

__device__ __forceinline__ float dot2acc(unsigned x, unsigned w, float acc) {
#if HAS_FDOT2
    return __builtin_amdgcn_fdot2(u2h(x), u2h(w), acc, false);
#else
    half2_t a = u2h(x), b = u2h(w);
    acc = fmaf((float)a.x, (float)b.x, acc);
    return fmaf((float)a.y, (float)b.y, acc);
#endif
}

// ---------------- binning kernels ----------------

__global__ __launch_bounds__(256) void zero_bins(unsigned* __restrict__ cnt) {
    int i = blockIdx.x * 256 + threadIdx.x;
    if (i < NBINS) cnt[i] = 0u;
}

__device__ __forceinline__ int bin_of(int b, int y, int x) {
    return b * BINS_PER_B + y * (WW >> XSHIFT) + (x >> XSHIFT);
}

__global__ __launch_bounds__(256) void hist_kernel(
    const int* __restrict__ voxel, unsigned* __restrict__ cnt) {
    int pid = blockIdx.x * 256 + threadIdx.x;
    if (pid >= NPTS) return;
    int b = pid / NN;
    int y = voxel[(size_t)pid * 3 + 1];
    int x = voxel[(size_t)pid * 3 + 2];
    atomicAdd(&cnt[bin_of(b, y, x)], 1u);
}

__global__ __launch_bounds__(1024) void scan_kernel(
    const unsigned* __restrict__ cnt, unsigned* __restrict__ off) {
    __shared__ unsigned lds[1024];
    int t = threadIdx.x;
    int base = t * (NBINS / 1024);           // 64 bins per thread
    unsigned sum = 0;
    #pragma unroll 4
    for (int i = 0; i < NBINS / 1024; ++i) sum += cnt[base + i];
    lds[t] = sum;
    __syncthreads();
    for (int d = 1; d < 1024; d <<= 1) {
        unsigned v = (t >= d) ? lds[t - d] : 0u;
        __syncthreads();
        lds[t] += v;
        __syncthreads();
    }
    unsigned run = (t == 0) ? 0u : lds[t - 1];
    for (int i = 0; i < NBINS / 1024; ++i) {
        unsigned c = cnt[base + i];
        off[base + i] = run;
        run += c;
    }
}

__global__ __launch_bounds__(256) void scatter_kernel(
    const int* __restrict__ voxel, unsigned* __restrict__ off,
    unsigned* __restrict__ order, unsigned* __restrict__ yx) {
    int pid = blockIdx.x * 256 + threadIdx.x;
    if (pid >= NPTS) return;
    int b = pid / NN;
    int y = voxel[(size_t)pid * 3 + 1];
    int x = voxel[(size_t)pid * 3 + 2];
    unsigned pos = atomicAdd(&off[bin_of(b, y, x)], 1u);
    order[pos] = (unsigned)pid;
    yx[pos] = ((unsigned)y << 16) | (unsigned)x;
}

// ---------------- weight preprocessing ----------------
// Wcat[160][32]: rows 0..63  = W_flow[0..63] @ W1top
//                rows 64..127 = W_pc[0..63]   @ W1bot
//                rows 128..159= W_pc[64..95]  @ W1bot   (fea rows)
// Wtail[6][32]: W_flow[64..69] @ W1top   (flows + pose rows)
// bcat[32] = b1 + b_flow @ W1top + b_pc @ W1bot
// W2h[q][p][j] (q=0..39, p=0..1, j=0..31): half2(Wcat[4q+2p][j], Wcat[4q+2p+1][j])

__global__ __launch_bounds__(256) void build_weights(
    const float* __restrict__ Wf, const float* __restrict__ bf,
    const float* __restrict__ Wp, const float* __restrict__ bp,
    const float* __restrict__ W1, const float* __restrict__ b1,
    float* __restrict__ wbuf)
{
    float* Wcat = wbuf;                       // 160*32
    float* Wtail = wbuf + 160 * 32;           // 6*32
    float* bcat = wbuf + 160 * 32 + 6 * 32;   // 32
    unsigned* W2h = (unsigned*)(wbuf + WCAT_PAD);  // 40*64
    int t = threadIdx.x;
    for (int idx = t; idx < 160 * 32; idx += 256) {
        int r = idx >> 5, j = idx & 31;
        float s = 0.f;
        if (r < 64) {
            for (int k = 0; k < 32; ++k) s += Wf[r * 32 + k] * W1[k * 32 + j];
        } else {
            int rr = r - 64;   // 0..95 pc row
            for (int k = 0; k < 32; ++k) s += Wp[rr * 32 + k] * W1[(32 + k) * 32 + j];
        }
        Wcat[idx] = s;
    }
    for (int idx = t; idx < 6 * 32; idx += 256) {
        int r = idx >> 5, j = idx & 31;
        float s = 0.f;
        for (int k = 0; k < 32; ++k) s += Wf[(64 + r) * 32 + k] * W1[k * 32 + j];
        Wtail[idx] = s;
    }
    for (int j = t; j < 32; j += 256) {
        float s = b1[j];
        for (int k = 0; k < 32; ++k)
            s += bf[k] * W1[k * 32 + j] + bp[k] * W1[(32 + k) * 32 + j];
        bcat[j] = s;
    }
    __syncthreads();
    for (int idx = t; idx < 40 * 64; idx += 256) {
        int q = idx >> 6, r = idx & 63;
        int p = r >> 5, j = r & 31;
        int row = 4 * q + 2 * p;
        W2h[idx] = packh(Wcat[row * 32 + j], Wcat[(row + 1) * 32 + j]);
    }
}

// ---------------- phase G: plane-parallel gather into packed f16 [g][s] ----

__global__ __launch_bounds__(256) void gather_pack(
    const float* __restrict__ pc0_map, const float* __restrict__ flow_map,
    const unsigned* __restrict__ order, const unsigned* __restrict__ yx,
    uint2* __restrict__ packed, int base, int n, int CN)
{
    int t = blockIdx.x * 256 + threadIdx.x;
    if (t >= n) return;
    int g = blockIdx.y;                     // 0..15 flow quads, 16..31 pc quads
    int s = base + t;
    unsigned p = yx[s];
    int y = (int)(p >> 16), x = (int)(p & 0xffffu);
    int b = (int)order[s] / NN;
    const float* m = (g < 16) ? flow_map : pc0_map;
    int c0 = (g & 15) * 4;
    size_t off = ((size_t)(b * CC + c0)) * HWSZ + (size_t)y * WW + x;
    float v0 = m[off];
    float v1 = m[off + HWSZ];
    float v2 = m[off + 2 * (size_t)HWSZ];
    float v3 = m[off + 3 * (size_t)HWSZ];
    uint2 o;
    o.x = packh(v0, v1);
    o.y = packh(v2, v3);
    packed[(size_t)g * CN + t] = o;
}

// ---------------- phase M: 2-pt/thread dot2 MLP ----------------

__global__ __launch_bounds__(256) void mlp3(
    const uint2* __restrict__ packed, int base, int n, int CN,
    const float* __restrict__ pc0_fea,
    const float* __restrict__ flows,
    const float* __restrict__ pose_flows,
    const float* __restrict__ radar_pose,
    const int*   __restrict__ point_idxes,
    const unsigned* __restrict__ order,
    const float* __restrict__ wbuf,
    const float* __restrict__ W2, const float* __restrict__ b2,
    const float* __restrict__ W3, const float* __restrict__ b3,
    float* __restrict__ out)
{
    const float* Wtail = wbuf + 160 * 32;
    const float* bcat  = wbuf + 160 * 32 + 6 * 32;
    const unsigned* Wh = (const unsigned*)(wbuf + WCAT_PAD);

    int t = threadIdx.x;
    int s0 = blockIdx.x * 512 + t;          // slot A (relative)
    int s1 = s0 + 256;                      // slot B
    bool v0 = s0 < n, v1 = s1 < n;
    int sa = v0 ? s0 : (n - 1);
    int sb = v1 ? s1 : (n - 1);
    int pidA = (int)order[base + sa];
    int pidB = (int)order[base + sb];
    int bA = pidA / NN, bB = pidB / NN;

    float zA[32], zB[32];
    #pragma unroll
    for (int j = 0; j < 32; ++j) { zA[j] = bcat[j]; zB[j] = bcat[j]; }

    // ---- tail: flows(3) + pose(3), f32 ----
    {
        const float* flA = flows + (size_t)pidA * 3;
        const float* flB = flows + (size_t)pidB * 3;
        float fA[6], fB[6];
        fA[0] = flA[0]; fA[1] = flA[1]; fA[2] = flA[2];
        fB[0] = flB[0]; fB[1] = flB[1]; fB[2] = flB[2];
        int piA = point_idxes[pidA];
        int piB = point_idxes[pidB];
        const float* psA = (piA < PP) ? (pose_flows + ((size_t)bA * PP + piA) * 3)
                                      : (radar_pose + ((size_t)bA * RP + (piA - PP)) * 3);
        const float* psB = (piB < PP) ? (pose_flows + ((size_t)bB * PP + piB) * 3)
                                      : (radar_pose + ((size_t)bB * RP + (piB - PP)) * 3);
        fA[3] = psA[0]; fA[4] = psA[1]; fA[5] = psA[2];
        fB[3] = psB[0]; fB[4] = psB[1]; fB[5] = psB[2];
        #pragma unroll
        for (int r = 0; r < 6; ++r) {
            #pragma unroll
            for (int j = 0; j < 32; ++j) {
                float w = Wtail[r * 32 + j];
                zA[j] = fmaf(fA[r], w, zA[j]);
                zB[j] = fmaf(fB[r], w, zB[j]);
            }
        }
    }

    // ---- fea part first (short live range for feah regs): quads 32..39 ----
    {
        unsigned fhA[16], fhB[16];
        const float4* qA = (const float4*)(pc0_fea + (size_t)pidA * 32);
        const float4* qB = (const float4*)(pc0_fea + (size_t)pidB * 32);
        #pragma unroll
        for (int k = 0; k < 8; ++k) {
            float4 a = qA[k], b = qB[k];
            fhA[2 * k] = packh(a.x, a.y); fhA[2 * k + 1] = packh(a.z, a.w);
            fhB[2 * k] = packh(b.x, b.y); fhB[2 * k + 1] = packh(b.z, b.w);
        }
        #pragma unroll
        for (int q = 0; q < 8; ++q) {
            const unsigned* wq = Wh + (32 + q) * 64;
            #pragma unroll
            for (int j = 0; j < 32; ++j) {
                unsigned w0 = wq[j], w1 = wq[32 + j];
                zA[j] = dot2acc(fhA[2 * q], w0, zA[j]);
                zA[j] = dot2acc(fhA[2 * q + 1], w1, zA[j]);
                zB[j] = dot2acc(fhB[2 * q], w0, zB[j]);
                zB[j] = dot2acc(fhB[2 * q + 1], w1, zB[j]);
            }
        }
    }

    // ---- main packed GEMM: quads 0..31 ----
    for (int q = 0; q < 32; ++q) {
        const unsigned* wq = Wh + q * 64;
        uint2 xa = packed[(size_t)q * CN + sa];
        uint2 xb = packed[(size_t)q * CN + sb];
        #pragma unroll
        for (int j = 0; j < 32; ++j) {
            unsigned w0 = wq[j], w1 = wq[32 + j];
            zA[j] = dot2acc(xa.x, w0, zA[j]);
            zA[j] = dot2acc(xa.y, w1, zA[j]);
            zB[j] = dot2acc(xb.x, w0, zB[j]);
            zB[j] = dot2acc(xb.y, w1, zB[j]);
        }
    }

    // ---- epilogue per point ----
    #pragma unroll
    for (int p = 0; p < 2; ++p) {
        float* z = p ? zB : zA;
        int pid = p ? pidB : pidA;
        bool valid = p ? v1 : v0;

        #pragma unroll
        for (int j = 0; j < 32; ++j) {
            float v = z[j];
            z[j] = 0.5f * v * (1.0f + erff(v * 0.70710678118654752f));
        }
        float h2[16];
        #pragma unroll
        for (int j = 0; j < 16; ++j) h2[j] = b2[j];
        #pragma unroll
        for (int i = 0; i < 32; ++i) {
            #pragma unroll
            for (int j = 0; j < 16; ++j) h2[j] = fmaf(z[i], W2[i * 16 + j], h2[j]);
        }
        #pragma unroll
        for (int j = 0; j < 16; ++j) {
            float v = h2[j];
            h2[j] = 0.5f * v * (1.0f + erff(v * 0.70710678118654752f));
        }
        float zz = b3[0];
        #pragma unroll
        for (int i = 0; i < 16; ++i) zz = fmaf(h2[i], W3[i], zz);
        float score = 1.0f / (1.0f + expf(-zz));

        if (valid) {
            out[(size_t)NPTS + pid] = score;
            out[pid] = (score > 0.5f) ? 1.0f : 0.0f;
        }
    }
}

extern "C" void kernel_launch(void* const* d_in, const int* in_sizes, int n_in,
                              void* d_out, int out_size, void* d_ws, size_t ws_size,
                              hipStream_t stream) {
    const float* pc0_map    = (const float*)d_in[0];
    const float* flow_map   = (const float*)d_in[1];
    const float* pc0_fea    = (const float*)d_in[2];
    const float* flows      = (const float*)d_in[3];
    const float* pose_flows = (const float*)d_in[4];
    const float* radar_pose = (const float*)d_in[5];
    const int*   voxel      = (const int*)d_in[6];
    const int*   pidx       = (const int*)d_in[7];
    const float* W_flow = (const float*)d_in[8];
    const float* b_flow = (const float*)d_in[9];
    const float* W_pc   = (const float*)d_in[10];
    const float* b_pc   = (const float*)d_in[11];
    const float* W1     = (const float*)d_in[12];
    const float* b1     = (const float*)d_in[13];
    const float* W2     = (const float*)d_in[14];
    const float* b2     = (const float*)d_in[15];
    const float* W3     = (const float*)d_in[16];
    const float* b3     = (const float*)d_in[17];

    // ws layout: cnt[NBINS] | off[NBINS] | order[NPTS] | yx[NPTS] | wbuf[WBUF_WORDS] | packed[]
    size_t sort_need = (size_t)(2 * NBINS + 2 * NPTS) * sizeof(unsigned);
    unsigned* cnt = (unsigned*)d_ws;
    unsigned* off = cnt + NBINS;
    unsigned* order = off + NBINS;
    unsigned* yx = order + NPTS;
    float* wbuf = (float*)(yx + NPTS);
    uint2* packed = (uint2*)(wbuf + WBUF_WORDS);

    size_t fixed_need = sort_need + (size_t)WBUF_WORDS * sizeof(float);

    int ptBlocks = (NPTS + 255) / 256;
    bool have_ws = ws_size >= fixed_need;
    if (!have_ws) return;   // harness provides ample ws (~>417MB observed)

    hipLaunchKernelGGL(zero_bins, dim3((NBINS + 255) / 256), dim3(256), 0, stream, cnt);
    hipLaunchKernelGGL(hist_kernel, dim3(ptBlocks), dim3(256), 0, stream, voxel, cnt);
    hipLaunchKernelGGL(scan_kernel, dim3(1), dim3(1024), 0, stream, cnt, off);
    hipLaunchKernelGGL(scatter_kernel, dim3(ptBlocks), dim3(256), 0, stream,
                       voxel, off, order, yx);
    hipLaunchKernelGGL(build_weights, dim3(1), dim3(256), 0, stream,
                       W_flow, b_flow, W_pc, b_pc, W1, b1, wbuf);

    size_t avail = (ws_size > fixed_need) ? (ws_size - fixed_need) : 0;
    long long cp = (long long)(avail / 256);     // 256 B per point (32 uint2)
    if (cp > NPTS) cp = NPTS;
    int CP = (int)(cp & ~511LL);
    if (CP < 512) return;

    for (int basePt = 0; basePt < NPTS; basePt += CP) {
        int n = NPTS - basePt;
        if (n > CP) n = CP;
        dim3 gG((n + 255) / 256, 32);
        hipLaunchKernelGGL(gather_pack, gG, dim3(256), 0, stream,
                           pc0_map, flow_map, order, yx, packed, basePt, n, CP);
        hipLaunchKernelGGL(mlp3, dim3((n + 511) / 512), dim3(256), 0, stream,
                           packed, basePt, n, CP,
                           pc0_fea, flows, pose_flows, radar_pose, pidx, order,
                           wbuf, W2, b2, W3, b3, (float*)d_out);
    }
}

// Round 6
// 357.428 us; speedup vs baseline: 1.9619x; 1.9619x over previous
//
#include <hip/hip_runtime.h>

#define NB 4
#define NN 200000
#define HH 512
#define WW 512
#define CC 64
#define PP 150000
#define RP 100000
#define HWSZ (HH * WW)
#define NPTS (NB * NN)
#define NTILES (NPTS / 16)                 // 50000 (exact)
#define XSHIFT 4                           // 16 floats = one 64B line along x
#define BINS_PER_B (HH * (WW >> XSHIFT))   // 16384
#define NBINS (NB * BINS_PER_B)            // 65536

// wbuf layout (32-bit words):
//   WB_WCAT  : 160*32 f32 collapsed layer-1 weights (staging)
//   WB_WTAIL : 6*32 f32 (flows+pose rows)
//   WB_BCAT  : 32 f32 folded bias
//   WB_BFRAG : [nt=2][t=6][lane=64][4 u32] f16-pair B-fragments (K=192 x N=32)
//   WB_BFRAG2: [lane=64][4 u32] B-fragment for layer2 (32x16)
#define WB_WCAT 0
#define WB_WTAIL 5120
#define WB_BCAT 5312
#define WB_BFRAG 5376
#define WB_BFRAG2 (WB_BFRAG + 3072)
#define WBUF_WORDS (WB_BFRAG2 + 256)       // 8704

typedef _Float16 half8_t __attribute__((ext_vector_type(8)));
typedef _Float16 half2_t __attribute__((ext_vector_type(2)));
typedef float f32x4 __attribute__((ext_vector_type(4)));

__device__ __forceinline__ unsigned packh(float a, float b) {
    half2_t h; h.x = (_Float16)a; h.y = (_Float16)b;
    unsigned u; __builtin_memcpy(&u, &h, 4); return u;
}
__device__ __forceinline__ float gelu(float v) {
    return 0.5f * v * (1.0f + erff(v * 0.70710678118654752f));
}

// ---------------- binning kernels ----------------

__global__ __launch_bounds__(256) void zero_bins(unsigned* __restrict__ cnt) {
    int i = blockIdx.x * 256 + threadIdx.x;
    if (i < NBINS) cnt[i] = 0u;
}

__device__ __forceinline__ int bin_of(int b, int y, int x) {
    return b * BINS_PER_B + y * (WW >> XSHIFT) + (x >> XSHIFT);
}

__global__ __launch_bounds__(256) void hist_kernel(
    const int* __restrict__ voxel, unsigned* __restrict__ cnt) {
    int pid = blockIdx.x * 256 + threadIdx.x;
    if (pid >= NPTS) return;
    int b = pid / NN;
    int y = voxel[(size_t)pid * 3 + 1];
    int x = voxel[(size_t)pid * 3 + 2];
    atomicAdd(&cnt[bin_of(b, y, x)], 1u);
}

__global__ __launch_bounds__(1024) void scan_kernel(
    const unsigned* __restrict__ cnt, unsigned* __restrict__ off) {
    __shared__ unsigned lds[1024];
    int t = threadIdx.x;
    int base = t * (NBINS / 1024);
    unsigned sum = 0;
    #pragma unroll 4
    for (int i = 0; i < NBINS / 1024; ++i) sum += cnt[base + i];
    lds[t] = sum;
    __syncthreads();
    for (int d = 1; d < 1024; d <<= 1) {
        unsigned v = (t >= d) ? lds[t - d] : 0u;
        __syncthreads();
        lds[t] += v;
        __syncthreads();
    }
    unsigned run = (t == 0) ? 0u : lds[t - 1];
    for (int i = 0; i < NBINS / 1024; ++i) {
        unsigned c = cnt[base + i];
        off[base + i] = run;
        run += c;
    }
}

__global__ __launch_bounds__(256) void scatter_kernel(
    const int* __restrict__ voxel, unsigned* __restrict__ off,
    unsigned* __restrict__ order, unsigned* __restrict__ yx) {
    int pid = blockIdx.x * 256 + threadIdx.x;
    if (pid >= NPTS) return;
    int b = pid / NN;
    int y = voxel[(size_t)pid * 3 + 1];
    int x = voxel[(size_t)pid * 3 + 2];
    unsigned pos = atomicAdd(&off[bin_of(b, y, x)], 1u);
    order[pos] = (unsigned)pid;
    yx[pos] = ((unsigned)y << 16) | (unsigned)x;
}

// ---------------- weight preprocessing ----------------
// Collapsed layer1 (no nonlinearity between input GEMMs and W1):
//   k 0..63   : W_flow[0..63]  @ W1top      (flow map channels)
//   k 64..127 : W_pc[0..63]    @ W1bot      (pc map channels)
//   k 128..159: W_pc[64..95]   @ W1bot      (pc0_fea)
//   k 160..165: W_flow[64..69] @ W1top      (flows3 + pose3)
//   k 166     : folded bias row (input "1")
//   k 167..191: zero

__device__ __forceinline__ float wrowf(const float* __restrict__ wbuf, int k, int col) {
    if (k < 160) return wbuf[WB_WCAT + k * 32 + col];
    if (k < 166) return wbuf[WB_WTAIL + (k - 160) * 32 + col];
    if (k == 166) return wbuf[WB_BCAT + col];
    return 0.f;
}

__global__ __launch_bounds__(256) void build_weights(
    const float* __restrict__ Wf, const float* __restrict__ bf,
    const float* __restrict__ Wp, const float* __restrict__ bp,
    const float* __restrict__ W1, const float* __restrict__ b1,
    const float* __restrict__ W2,
    float* __restrict__ wbuf)
{
    float* Wcat = wbuf + WB_WCAT;
    float* Wtail = wbuf + WB_WTAIL;
    float* bcat = wbuf + WB_BCAT;
    int t = threadIdx.x;
    for (int idx = t; idx < 160 * 32; idx += 256) {
        int r = idx >> 5, j = idx & 31;
        float s = 0.f;
        if (r < 64) {
            for (int k = 0; k < 32; ++k) s += Wf[r * 32 + k] * W1[k * 32 + j];
        } else {
            int rr = r - 64;   // pc rows 0..95
            for (int k = 0; k < 32; ++k) s += Wp[rr * 32 + k] * W1[(32 + k) * 32 + j];
        }
        Wcat[idx] = s;
    }
    for (int idx = t; idx < 6 * 32; idx += 256) {
        int r = idx >> 5, j = idx & 31;
        float s = 0.f;
        for (int k = 0; k < 32; ++k) s += Wf[(64 + r) * 32 + k] * W1[k * 32 + j];
        Wtail[idx] = s;
    }
    for (int j = t; j < 32; j += 256) {
        float s = b1[j];
        for (int k = 0; k < 32; ++k)
            s += bf[k] * W1[k * 32 + j] + bp[k] * W1[(32 + k) * 32 + j];
        bcat[j] = s;
    }
    __syncthreads();
    // B-fragments for layer1 MFMA (f16 pairs): lane l supplies
    // B[k = t*32 + (l>>4)*8 + j][col = nt*16 + (l&15)]
    unsigned* BF = (unsigned*)(wbuf + WB_BFRAG);
    for (int idx = t; idx < 2 * 6 * 64 * 4; idx += 256) {
        int w = idx & 3;
        int slot = idx >> 2;          // (nt*6+tt)*64 + l
        int l = slot & 63;
        int rest = slot >> 6;         // 0..11
        int tt = rest % 6, nt = rest / 6;
        int k = tt * 32 + (l >> 4) * 8 + w * 2;
        int col = nt * 16 + (l & 15);
        BF[idx] = packh(wrowf(wbuf, k, col), wrowf(wbuf, k + 1, col));
    }
    // layer2 B-fragment: B[k2 = (l>>4)*8+j][col = l&15] = W2[k2*16+col]
    for (int idx = t; idx < 64 * 4; idx += 256) {
        int w = idx & 3, l = idx >> 2;
        int k2 = (l >> 4) * 8 + w * 2, col = l & 15;
        BF[3072 + idx] = packh(W2[k2 * 16 + col], W2[(k2 + 1) * 16 + col]);
    }
}

// ---------------- fused gather + MFMA MLP ----------------
// One wave per 16-point tile of the sorted order. Each lane gathers ITS OWN
// A-fragment (point = l&15, k = t*32 + (l>>4)*8 + j) straight from HBM.

__global__ __launch_bounds__(256) void mlp_fused(
    const float* __restrict__ pc0_map, const float* __restrict__ flow_map,
    const float* __restrict__ pc0_fea, const float* __restrict__ flows,
    const float* __restrict__ pose_flows, const float* __restrict__ radar_pose,
    const int* __restrict__ point_idxes,
    const unsigned* __restrict__ order, const unsigned* __restrict__ yx,
    const float* __restrict__ wbuf,
    const float* __restrict__ b2, const float* __restrict__ W3,
    const float* __restrict__ b3,
    float* __restrict__ out)
{
    __shared__ uint4 Bf[832];                       // 2*6*64 layer1 + 64 layer2
    __shared__ __align__(16) _Float16 zl[4][16 * 48];  // per-wave z bounce (48-ch pad)

    {
        const unsigned* wsrc = (const unsigned*)(wbuf + WB_BFRAG);
        unsigned* dst = (unsigned*)Bf;
        for (int i = threadIdx.x; i < 832 * 4; i += 256) dst[i] = wsrc[i];
    }
    __syncthreads();

    int wave = threadIdx.x >> 6;
    int l = threadIdx.x & 63;
    int lo = l & 15, hi = l >> 4;
    int tile = blockIdx.x * 4 + wave;
    if (tile >= NTILES) return;
    int s0 = tile * 16;

    int pid = (int)order[s0 + lo];
    unsigned pyx = yx[s0 + lo];
    int y = (int)(pyx >> 16), x = (int)(pyx & 0xffffu);
    int b = pid / NN;

    const float* fm = flow_map + ((size_t)b * CC) * HWSZ + (size_t)y * WW + x;
    const float* pm = pc0_map  + ((size_t)b * CC) * HWSZ + (size_t)y * WW + x;

    half8_t A[6];
    // t = 0..3: map channels (t0,t1 = flow 0..63; t2,t3 = pc 0..63)
    #pragma unroll
    for (int t = 0; t < 4; ++t) {
        const float* mp = (t < 2) ? fm : pm;
        int ch0 = (t & 1) * 32 + hi * 8;
        float v[8];
        #pragma unroll
        for (int j = 0; j < 8; ++j) v[j] = mp[(size_t)(ch0 + j) * HWSZ];
        #pragma unroll
        for (int j = 0; j < 8; ++j) A[t][j] = (_Float16)v[j];
    }
    // t = 4: pc0_fea
    {
        const float* fe = pc0_fea + (size_t)pid * 32 + hi * 8;
        float4 fa = *(const float4*)fe;
        float4 fb = *(const float4*)(fe + 4);
        A[4][0] = (_Float16)fa.x; A[4][1] = (_Float16)fa.y;
        A[4][2] = (_Float16)fa.z; A[4][3] = (_Float16)fa.w;
        A[4][4] = (_Float16)fb.x; A[4][5] = (_Float16)fb.y;
        A[4][6] = (_Float16)fb.z; A[4][7] = (_Float16)fb.w;
    }
    // t = 5: tail (flows3, pose3, ones-row for bias, zeros)
    {
        half8_t a5;
        #pragma unroll
        for (int j = 0; j < 8; ++j) a5[j] = (_Float16)0.0f;
        if (hi == 0) {
            const float* fl = flows + (size_t)pid * 3;
            int pi = point_idxes[pid];
            const float* ps = (pi < PP) ? (pose_flows + ((size_t)b * PP + pi) * 3)
                                        : (radar_pose + ((size_t)b * RP + (pi - PP)) * 3);
            a5[0] = (_Float16)fl[0]; a5[1] = (_Float16)fl[1]; a5[2] = (_Float16)fl[2];
            a5[3] = (_Float16)ps[0]; a5[4] = (_Float16)ps[1]; a5[5] = (_Float16)ps[2];
            a5[6] = (_Float16)1.0f;
        }
        A[5] = a5;
    }

    // layer1 (collapsed): z[16 pts][32 ch] = A(16x192) * B(192x32)
    f32x4 acc0 = {0.f, 0.f, 0.f, 0.f};
    f32x4 acc1 = {0.f, 0.f, 0.f, 0.f};
    #pragma unroll
    for (int t = 0; t < 6; ++t) {
        half8_t B0, B1;
        uint4 u0 = Bf[t * 64 + l];
        uint4 u1 = Bf[(6 + t) * 64 + l];
        __builtin_memcpy(&B0, &u0, 16);
        __builtin_memcpy(&B1, &u1, 16);
        acc0 = __builtin_amdgcn_mfma_f32_16x16x32_f16(A[t], B0, acc0, 0, 0, 0);
        acc1 = __builtin_amdgcn_mfma_f32_16x16x32_f16(A[t], B1, acc1, 0, 0, 0);
    }

    // gelu -> z LDS (f16), C-layout: point = hi*4+r, ch = nt*16+lo
    _Float16* zw = zl[wave];
    #pragma unroll
    for (int r = 0; r < 4; ++r) {
        zw[(hi * 4 + r) * 48 + lo]      = (_Float16)gelu(acc0[r]);
        zw[(hi * 4 + r) * 48 + 16 + lo] = (_Float16)gelu(acc1[r]);
    }

    // layer2: h2[16 pts][16] = gelu(z)(16x32) * W2(32x16); A-layout read
    half8_t A2, B2;
    __builtin_memcpy(&A2, &zw[lo * 48 + hi * 8], 16);
    {
        uint4 u2 = Bf[768 + l];
        __builtin_memcpy(&B2, &u2, 16);
    }
    f32x4 zero = {0.f, 0.f, 0.f, 0.f};
    f32x4 acc2 = __builtin_amdgcn_mfma_f32_16x16x32_f16(A2, B2, zero, 0, 0, 0);

    // epilogue: +b2, gelu, dot with W3 (reduce over 16 channel-lanes), sigmoid
    float b2v = b2[lo];
    float w3v = W3[lo];
    float t0 = gelu(acc2[0] + b2v) * w3v;
    float t1 = gelu(acc2[1] + b2v) * w3v;
    float t2 = gelu(acc2[2] + b2v) * w3v;
    float t3 = gelu(acc2[3] + b2v) * w3v;
    #pragma unroll
    for (int m = 1; m <= 8; m <<= 1) {
        t0 += __shfl_xor(t0, m);
        t1 += __shfl_xor(t1, m);
        t2 += __shfl_xor(t2, m);
        t3 += __shfl_xor(t3, m);
    }
    if (lo < 4) {
        float zz = (lo == 0 ? t0 : lo == 1 ? t1 : lo == 2 ? t2 : t3) + b3[0];
        float score = 1.0f / (1.0f + expf(-zz));
        int p2 = hi * 4 + lo;
        int pid2 = (int)order[s0 + p2];
        out[(size_t)NPTS + pid2] = score;
        out[pid2] = (score > 0.5f) ? 1.0f : 0.0f;
    }
}

extern "C" void kernel_launch(void* const* d_in, const int* in_sizes, int n_in,
                              void* d_out, int out_size, void* d_ws, size_t ws_size,
                              hipStream_t stream) {
    const float* pc0_map    = (const float*)d_in[0];
    const float* flow_map   = (const float*)d_in[1];
    const float* pc0_fea    = (const float*)d_in[2];
    const float* flows      = (const float*)d_in[3];
    const float* pose_flows = (const float*)d_in[4];
    const float* radar_pose = (const float*)d_in[5];
    const int*   voxel      = (const int*)d_in[6];
    const int*   pidx       = (const int*)d_in[7];
    const float* W_flow = (const float*)d_in[8];
    const float* b_flow = (const float*)d_in[9];
    const float* W_pc   = (const float*)d_in[10];
    const float* b_pc   = (const float*)d_in[11];
    const float* W1     = (const float*)d_in[12];
    const float* b1     = (const float*)d_in[13];
    const float* W2     = (const float*)d_in[14];
    const float* b2     = (const float*)d_in[15];
    const float* W3     = (const float*)d_in[16];
    const float* b3     = (const float*)d_in[17];

    // ws layout: cnt[NBINS] | off[NBINS] | order[NPTS] | yx[NPTS] | wbuf[WBUF_WORDS]
    size_t need = (size_t)(2 * NBINS + 2 * NPTS) * sizeof(unsigned)
                + (size_t)WBUF_WORDS * sizeof(float);
    if (ws_size < need) return;
    unsigned* cnt = (unsigned*)d_ws;
    unsigned* off = cnt + NBINS;
    unsigned* order = off + NBINS;
    unsigned* yx = order + NPTS;
    float* wbuf = (float*)(yx + NPTS);

    int ptBlocks = (NPTS + 255) / 256;

    hipLaunchKernelGGL(zero_bins, dim3((NBINS + 255) / 256), dim3(256), 0, stream, cnt);
    hipLaunchKernelGGL(hist_kernel, dim3(ptBlocks), dim3(256), 0, stream, voxel, cnt);
    hipLaunchKernelGGL(scan_kernel, dim3(1), dim3(1024), 0, stream, cnt, off);
    hipLaunchKernelGGL(scatter_kernel, dim3(ptBlocks), dim3(256), 0, stream,
                       voxel, off, order, yx);
    hipLaunchKernelGGL(build_weights, dim3(1), dim3(256), 0, stream,
                       W_flow, b_flow, W_pc, b_pc, W1, b1, W2, wbuf);

    hipLaunchKernelGGL(mlp_fused, dim3(NTILES / 4), dim3(256), 0, stream,
                       pc0_map, flow_map, pc0_fea, flows, pose_flows, radar_pose,
                       pidx, order, yx, wbuf, b2, W3, b3, (float*)d_out);
}